// Round 2
// baseline (20842.584 us; speedup 1.0000x reference)
//
#include <hip/hip_runtime.h>

// SCNN 4-pass directional message passing, persistent-kernel formulation.
// Each pass: out[i] = x[i] + relu(conv1d_C128K9(out[i+1])), scanned from the
// high end (reverse=True). One persistent kernel per pass; block = one batch n;
// 4 waves = 4 co-tiles of 32; scan recurrence stepped with __syncthreads only.
// Conv done as 9 tap-GEMMs (K=128) with mfma_f32_32x32x16_bf16; weights live
// in VGPRs (72 frags = 288 regs), prev-row activations ping-pong in LDS (bf16).

typedef __attribute__((ext_vector_type(8))) short short8;
typedef __attribute__((ext_vector_type(16))) float f32x16;

#define C_ 128
#define H_ 128
#define W_ 192
#define HW_ (H_*W_)
#define CHW_ (C_*HW_)
#define N_ 4

__device__ __forceinline__ unsigned short f2bf(float f) {
    unsigned int u = __float_as_uint(f);
    return (unsigned short)((u + 0x7FFFu + ((u >> 16) & 1u)) >> 16);
}

// wfrag layout: [(pass*4+ct)][kk 9][cc 8][lane 64][j 8] bf16 as ushort.
// Element = w[co = ct*32 + (lane&31)][ci = cc*16 + (lane>>5)*8 + j][kk]
// i.e. exactly the A-fragment each lane needs for mfma_f32_32x32x16_bf16.
__global__ __launch_bounds__(256) void prep_weights(
        const float* __restrict__ w0, const float* __restrict__ w1,
        const float* __restrict__ w2, const float* __restrict__ w3,
        unsigned short* __restrict__ wf)
{
    const int idx = blockIdx.x * 256 + threadIdx.x;   // 73728 total
    const int lane = idx & 63;
    const int cc   = (idx >> 6) & 7;
    const int kq   = idx >> 9;        // 0..143
    const int kk   = kq % 9;
    const int ctp  = kq / 9;          // pass*4 + ct
    const int ct   = ctp & 3, p = ctp >> 2;
    const float* w = (p == 0) ? w0 : (p == 1) ? w1 : (p == 2) ? w2 : w3;
    const int co  = ct * 32 + (lane & 31);
    const int ci0 = cc * 16 + (lane >> 5) * 8;
    unsigned short tmp[8];
    #pragma unroll
    for (int j = 0; j < 8; ++j)
        tmp[j] = f2bf(w[(size_t)(co * C_ + ci0 + j) * 9 + kk]);
    *(int4*)(wf + (size_t)idx * 8) = *(const int4*)tmp;
}

// NT = 32-wide t-tiles per line (192/32=6 vertical, 128/32=4 horizontal)
// L  = line length, SS = element stride between scan rows, SL = stride along line
template<int NT, int L, int SS, int SL>
__global__ __launch_bounds__(256, 1) void scnn_pass(
        float* __restrict__ out, const unsigned short* __restrict__ wfp, int Ls)
{
    constexpr int TPG  = NT / 2;          // tiles per group (acc pressure split)
    constexpr int PLSZ = (L + 8) * 136;   // one bf16 row buffer (ushort units)
    extern __shared__ unsigned short pl[];  // [2][L+8][136]

    const int tid    = threadIdx.x;
    const int ct     = tid >> 6;          // wave = co-tile (32 co)
    const int lane   = tid & 63;
    const int lane31 = lane & 31;
    const int cih    = (lane >> 5) * 8;   // k-half within chunk
    const int n      = blockIdx.x;
    float* outn = out + (size_t)n * CHW_;

    // Hold the entire weight tile for this co-tile in VGPRs (72 frags).
    short8 A[9][8];
    {
        const unsigned short* wct = wfp + (size_t)ct * (9 * 8 * 64 * 8);
        #pragma unroll
        for (int kk = 0; kk < 9; ++kk)
            #pragma unroll
            for (int cc = 0; cc < 8; ++cc)
                A[kk][cc] = *(const short8*)(wct + ((kk * 8 + cc) * 64 + lane) * 8);
    }

    // Zero halo rows (t<0, t>=L → conv 'same' padding) of both buffers.
    for (int idx = tid; idx < 2 * 8 * 136; idx += 256) {
        int b  = idx / (8 * 136);
        int rr = (idx / 136) & 7;
        int c  = idx % 136;
        int row = (rr < 4) ? rr : (L + rr);   // rows 0..3 and L+4..L+7
        pl[b * PLSZ + row * 136 + c] = 0;
    }
    // Fill buffer 0 interior with bf16 of scan row Ls-1 (unchanged passthrough row).
    {
        const int base0 = (Ls - 1) * SS;
        for (int idx = tid; idx < C_ * L; idx += 256) {
            int t = idx % L, ci = idx / L;
            pl[(t + 4) * 136 + ci] = f2bf(outn[(size_t)ci * HW_ + base0 + (size_t)t * SL]);
        }
    }
    __syncthreads();

    for (int s = 0; s < Ls - 1; ++s) {
        const unsigned short* plc = pl + (s & 1) * PLSZ;        // prev row (read)
        unsigned short* pld       = pl + ((s & 1) ^ 1) * PLSZ;  // this row (write)
        const int base_i = (Ls - 2 - s) * SS;

        #pragma unroll
        for (int g = 0; g < 2; ++g) {
            f32x16 acc[TPG];
            #pragma unroll
            for (int tt = 0; tt < TPG; ++tt)
                #pragma unroll
                for (int r = 0; r < 16; ++r) acc[tt][r] = 0.f;

            // 9 taps x 8 ci-chunks x TPG t-tiles of mfma_f32_32x32x16_bf16
            #pragma unroll
            for (int kk = 0; kk < 9; ++kk)
                #pragma unroll
                for (int cc = 0; cc < 8; ++cc)
                    #pragma unroll
                    for (int tt = 0; tt < TPG; ++tt) {
                        const unsigned short* bp = plc
                            + ((g * TPG + tt) * 32 + lane31 + kk) * 136 + cc * 16 + cih;
                        acc[tt] = __builtin_amdgcn_mfma_f32_32x32x16_bf16(
                                      A[kk][cc], *(const short8*)bp, acc[tt], 0, 0, 0);
                    }

            // epilogue: out = x + relu(conv) in fp32 (in-place), bf16 copy to pld
            #pragma unroll
            for (int tt = 0; tt < TPG; ++tt) {
                const int tg = (g * TPG + tt) * 32 + lane31;
                #pragma unroll
                for (int r = 0; r < 16; r += 2) {
                    const int co = ct * 32 + (r & 3) + 8 * (r >> 2) + 4 * (lane >> 5);
                    const size_t o0 = (size_t)co * HW_ + base_i + (size_t)tg * SL;
                    float v0 = outn[o0]       + fmaxf(acc[tt][r],     0.f);
                    float v1 = outn[o0 + HW_] + fmaxf(acc[tt][r + 1], 0.f);
                    outn[o0]       = v0;
                    outn[o0 + HW_] = v1;
                    *(unsigned int*)(pld + (tg + 4) * 136 + co) =
                        (unsigned int)f2bf(v0) | ((unsigned int)f2bf(v1) << 16);
                }
            }
        }
        __syncthreads();   // one barrier per scan row
    }
}

extern "C" void kernel_launch(void* const* d_in, const int* in_sizes, int n_in,
                              void* d_out, int out_size, void* d_ws, size_t ws_size,
                              hipStream_t stream)
{
    const float* x    = (const float*)d_in[0];
    const float* w_ud = (const float*)d_in[1];
    const float* w_du = (const float*)d_in[2];
    const float* w_lr = (const float*)d_in[3];
    const float* w_rl = (const float*)d_in[4];
    float* out = (float*)d_out;
    unsigned short* wf = (unsigned short*)d_ws;   // 1,179,648 B of ws used

    hipFuncSetAttribute(reinterpret_cast<const void*>(&scnn_pass<6,192,192,1>),
                        hipFuncAttributeMaxDynamicSharedMemorySize, 131072);
    hipFuncSetAttribute(reinterpret_cast<const void*>(&scnn_pass<4,128,1,192>),
                        hipFuncAttributeMaxDynamicSharedMemorySize, 131072);

    hipMemcpyAsync(out, x, sizeof(float) * (size_t)N_ * CHW_,
                   hipMemcpyDeviceToDevice, stream);
    prep_weights<<<288, 256, 0, stream>>>(w_ud, w_du, w_lr, w_rl, wf);

    constexpr int SHV = 2 * (192 + 8) * 136 * 2;   // 108,800 B
    constexpr int SHH = 2 * (128 + 8) * 136 * 2;   //  73,984 B
    for (int p = 0; p < 4; ++p) {
        const unsigned short* wfp = wf + (size_t)p * 4 * (9 * 8 * 64 * 8);
        if (p < 2) scnn_pass<6,192,192,1><<<N_, 256, SHV, stream>>>(out, wfp, H_);
        else       scnn_pass<4,128,1,192><<<N_, 256, SHH, stream>>>(out, wfp, W_);
    }
}

// Round 3
// 20074.844 us; speedup vs baseline: 1.0382x; 1.0382x over previous
//
#include <hip/hip_runtime.h>

// SCNN 4-pass directional message passing, persistent-kernel formulation.
// out[i] = x[i] + relu(conv1d_C128K9(out[i+1])), scanned high->low (reverse).
// One persistent kernel per pass; block = one batch n; 4 waves = 4 co-tiles.
// Conv = 9 tap-GEMMs (K=128ci) with mfma_f32_32x32x16_bf16. Weights are
// re-read per tap from global (L2-resident) to keep VGPR demand ~200 (R2's
// hold-all-weights-in-VGPR design spilled: 541MB/pass scratch writes).
// Horizontal passes run on a transposed [n][c][w][h] copy in d_ws so the
// scan line is contiguous (SL=1) — avoids 4B-scatter RMW (~2MB/step L2).

typedef __attribute__((ext_vector_type(8))) short short8;
typedef __attribute__((ext_vector_type(16))) float f32x16;

#define C_ 128
#define H_ 128
#define W_ 192
#define HW_ (H_*W_)
#define CHW_ (C_*HW_)
#define N_ 4

__device__ __forceinline__ unsigned short f2bf(float f) {
    unsigned int u = __float_as_uint(f);
    return (unsigned short)((u + 0x7FFFu + ((u >> 16) & 1u)) >> 16);
}

// wfrag layout: [(pass*4+ct)][kk 9][cc 8][lane 64][j 8] bf16 as ushort.
// Element = w[co = ct*32 + (lane&31)][ci = cc*16 + (lane>>5)*8 + j][kk]
__global__ __launch_bounds__(256) void prep_weights(
        const float* __restrict__ w0, const float* __restrict__ w1,
        const float* __restrict__ w2, const float* __restrict__ w3,
        unsigned short* __restrict__ wf)
{
    const int idx = blockIdx.x * 256 + threadIdx.x;   // 73728 total
    const int lane = idx & 63;
    const int cc   = (idx >> 6) & 7;
    const int kq   = idx >> 9;        // 0..143
    const int kk   = kq % 9;
    const int ctp  = kq / 9;          // pass*4 + ct
    const int ct   = ctp & 3, p = ctp >> 2;
    const float* w = (p == 0) ? w0 : (p == 1) ? w1 : (p == 2) ? w2 : w3;
    const int co  = ct * 32 + (lane & 31);
    const int ci0 = cc * 16 + (lane >> 5) * 8;
    unsigned short tmp[8];
    #pragma unroll
    for (int j = 0; j < 8; ++j)
        tmp[j] = f2bf(w[(size_t)(co * C_ + ci0 + j) * 9 + kk]);
    *(int4*)(wf + (size_t)idx * 8) = *(const int4*)tmp;
}

// Tiled transpose of each [R][C] image -> [C][R]. Grid (C/32, R/32, N*C_).
template<int R, int C>
__global__ __launch_bounds__(256) void transpose_rc(const float* __restrict__ src,
                                                    float* __restrict__ dst)
{
    __shared__ float tile[32][33];
    const int tx = threadIdx.x, ty = threadIdx.y;          // 32 x 8
    const int c0 = blockIdx.x * 32, r0 = blockIdx.y * 32;
    const size_t img = (size_t)blockIdx.z * (R * C);
    const float* s = src + img;
    float* d = dst + img;
    #pragma unroll
    for (int i = 0; i < 4; ++i)
        tile[ty + i * 8][tx] = s[(size_t)(r0 + ty + i * 8) * C + c0 + tx];
    __syncthreads();
    #pragma unroll
    for (int i = 0; i < 4; ++i)
        d[(size_t)(c0 + ty + i * 8) * R + r0 + tx] = tile[tx][ty + i * 8];
}

// NT = 32-wide t-tiles per line; L = line length; SS = stride between scan
// rows; SL = stride along line. Ls = scan length (runtime).
template<int NT, int L, int SS, int SL>
__global__ __launch_bounds__(256, 1) void scnn_pass(
        float* __restrict__ out, const unsigned short* __restrict__ wfp, int Ls)
{
    constexpr int PLSZ = (L + 8) * 136;     // one bf16 row buffer (ushort units)
    extern __shared__ unsigned short pl[];  // [2][L+8][136]

    const int tid    = threadIdx.x;
    const int ct     = tid >> 6;          // wave = co-tile (32 co)
    const int lane   = tid & 63;
    const int lane31 = lane & 31;
    const int cih    = (lane >> 5) * 8;   // ci-half within 16-chunk
    const int n      = blockIdx.x;
    float* outn = out + (size_t)n * CHW_;
    const unsigned short* wct = wfp + (size_t)ct * (9 * 8 * 64 * 8);

    // Zero halo rows (positions t<0 and t>=L -> conv 'same' padding).
    for (int idx = tid; idx < 2 * 8 * 136; idx += 256) {
        int b  = idx / (8 * 136);
        int rr = (idx / 136) & 7;
        int c  = idx % 136;
        int row = (rr < 4) ? rr : (L + rr);   // rows 0..3 and L+4..L+7
        pl[b * PLSZ + row * 136 + c] = 0;
    }
    // Fill buffer 0 interior with bf16 of scan row Ls-1 (passthrough row).
    {
        const int base0 = (Ls - 1) * SS;
        for (int idx = tid; idx < C_ * L; idx += 256) {
            int t = idx % L, ci = idx / L;
            pl[(t + 4) * 136 + ci] = f2bf(outn[(size_t)ci * HW_ + base0 + (size_t)t * SL]);
        }
    }
    __syncthreads();

    for (int s = 0; s < Ls - 1; ++s) {
        const unsigned short* plc = pl + (s & 1) * PLSZ;        // prev row (read)
        unsigned short* pld       = pl + ((s & 1) ^ 1) * PLSZ;  // this row (write)
        const int base_i = (Ls - 2 - s) * SS;

        f32x16 acc[NT];
        #pragma unroll
        for (int tt = 0; tt < NT; ++tt)
            #pragma unroll
            for (int r = 0; r < 16; ++r) acc[tt][r] = 0.f;

        #pragma unroll
        for (int kk = 0; kk < 9; ++kk) {
            short8 A[8];
            #pragma unroll
            for (int cc = 0; cc < 8; ++cc)
                A[cc] = *(const short8*)(wct + ((size_t)(kk * 8 + cc) * 64 + lane) * 8);
            #pragma unroll
            for (int cc = 0; cc < 8; ++cc)
                #pragma unroll
                for (int tt = 0; tt < NT; ++tt) {
                    const unsigned short* bp = plc
                        + (tt * 32 + lane31 + kk) * 136 + cc * 16 + cih;
                    acc[tt] = __builtin_amdgcn_mfma_f32_32x32x16_bf16(
                                  A[cc], *(const short8*)bp, acc[tt], 0, 0, 0);
                }
            // Stop the unroller from hoisting all 72 weight loads to the top
            // (that demands 288 VGPRs and re-creates R2's scratch spill).
            __builtin_amdgcn_sched_barrier(0);
        }

        // epilogue: out = x + relu(conv) fp32 in-place; bf16 copy to next buf.
        #pragma unroll
        for (int tt = 0; tt < NT; ++tt) {
            const int tg = tt * 32 + lane31;
            #pragma unroll
            for (int r = 0; r < 16; r += 2) {
                const int co = ct * 32 + (r & 3) + 8 * (r >> 2) + 4 * (lane >> 5);
                const size_t o0 = (size_t)co * HW_ + base_i + (size_t)tg * SL;
                float v0 = outn[o0]            + fmaxf(acc[tt][r],     0.f);
                float v1 = outn[o0 + (size_t)HW_] + fmaxf(acc[tt][r + 1], 0.f);
                outn[o0]               = v0;
                outn[o0 + (size_t)HW_] = v1;
                *(unsigned int*)(pld + (tg + 4) * 136 + co) =
                    (unsigned int)f2bf(v0) | ((unsigned int)f2bf(v1) << 16);
            }
        }
        __syncthreads();   // one barrier per scan row
    }
}

extern "C" void kernel_launch(void* const* d_in, const int* in_sizes, int n_in,
                              void* d_out, int out_size, void* d_ws, size_t ws_size,
                              hipStream_t stream)
{
    const float* x    = (const float*)d_in[0];
    const float* w_ud = (const float*)d_in[1];
    const float* w_du = (const float*)d_in[2];
    const float* w_lr = (const float*)d_in[3];
    const float* w_rl = (const float*)d_in[4];
    float* out = (float*)d_out;

    unsigned short* wf = (unsigned short*)d_ws;            // 1,179,648 B
    const size_t WS2_OFF = 2u * 1024u * 1024u;
    float* ws2 = (float*)((char*)d_ws + WS2_OFF);          // 50,331,648 B
    const bool use_tr = ws_size >= WS2_OFF + sizeof(float) * (size_t)N_ * CHW_;

    hipFuncSetAttribute(reinterpret_cast<const void*>(&scnn_pass<6,192,192,1>),
                        hipFuncAttributeMaxDynamicSharedMemorySize, 131072);
    hipFuncSetAttribute(reinterpret_cast<const void*>(&scnn_pass<4,128,128,1>),
                        hipFuncAttributeMaxDynamicSharedMemorySize, 131072);
    hipFuncSetAttribute(reinterpret_cast<const void*>(&scnn_pass<4,128,1,192>),
                        hipFuncAttributeMaxDynamicSharedMemorySize, 131072);

    hipMemcpyAsync(out, x, sizeof(float) * (size_t)N_ * CHW_,
                   hipMemcpyDeviceToDevice, stream);
    prep_weights<<<288, 256, 0, stream>>>(w_ud, w_du, w_lr, w_rl, wf);

    constexpr int SHV = 2 * (192 + 8) * 136 * 2;   // 108,800 B
    constexpr int SHH = 2 * (128 + 8) * 136 * 2;   //  73,984 B
    constexpr size_t WFP = 4 * (9 * 8 * 64 * 8);   // frags per pass (ushorts)

    // Passes 1,2: vertical scan over h, contiguous conv line along w.
    scnn_pass<6,192,192,1><<<N_, 256, SHV, stream>>>(out, wf + 0 * WFP, H_);
    scnn_pass<6,192,192,1><<<N_, 256, SHV, stream>>>(out, wf + 1 * WFP, H_);

    if (use_tr) {
        // Transpose to [n][c][w][h]; passes 3,4 scan over w with contiguous
        // conv line along h; transpose back.
        transpose_rc<H_, W_><<<dim3(W_/32, H_/32, N_*C_), dim3(32,8), 0, stream>>>(out, ws2);
        scnn_pass<4,128,128,1><<<N_, 256, SHH, stream>>>(ws2, wf + 2 * WFP, W_);
        scnn_pass<4,128,128,1><<<N_, 256, SHH, stream>>>(ws2, wf + 3 * WFP, W_);
        transpose_rc<W_, H_><<<dim3(H_/32, W_/32, N_*C_), dim3(32,8), 0, stream>>>(ws2, out);
    } else {
        scnn_pass<4,128,1,192><<<N_, 256, SHH, stream>>>(out, wf + 2 * WFP, W_);
        scnn_pass<4,128,1,192><<<N_, 256, SHH, stream>>>(out, wf + 3 * WFP, W_);
    }
}

// Round 6
// 10480.315 us; speedup vs baseline: 1.9887x; 1.9155x over previous
//
#include <hip/hip_runtime.h>

// SCNN 4-pass directional message passing.
// out[i] = x[i] + relu(conv1d_C128K9(out[i+1])), scan high->low, 4 passes
// (2 vertical over h, 2 horizontal over w; horizontal runs on a transposed
// [n][c][w][h] copy in d_ws so scan lines are contiguous).
//
// R5 = R4 + THE FIX: P is double-buffered again (R4 collapsed it to one
// buffer; conv taps cross the g-group boundary by ±4 positions, so g=1 read
// row-r+1 data that g=0's finalize had already overwritten with row r ->
// absmax 2.06). Read plc=P[s&1], write pld=P[(s&1)^1], like R3 (which passed).
//
//  - one kernel per PASS-PAIR: grid (4 n, 2 roles); role1 (pass p+1) trails
//    role0 (pass p) by one scan row via device-scope flag (release/acquire).
//  - 8 waves/block; wave pair (co-tile 32) splits ci in half -> 36 A-frags
//    = 144 VGPR/wave held in registers all pass (no per-step weight reload).
//  - partial sums exchanged through LDS (EX); epilogue split by row-half;
//    acc processed in 2 groups of NT/2 tiles to keep regs <= 256.
//  - x values prefetched to registers at group start (latency hidden under
//    the MFMA group); stores fire-and-forget.

typedef __attribute__((ext_vector_type(8))) short short8;
typedef __attribute__((ext_vector_type(16))) float f32x16;

#define C_ 128
#define H_ 128
#define W_ 192
#define HW_ (H_*W_)
#define CHW_ (C_*HW_)
#define N_ 4

__device__ __forceinline__ unsigned short f2bf(float f) {
    unsigned int u = __float_as_uint(f);
    return (unsigned short)((u + 0x7FFFu + ((u >> 16) & 1u)) >> 16);
}

// wfrag layout: [(pass*4+ct)][kk 9][cc 8][lane 64][j 8] bf16 as ushort.
// Element = w[co = ct*32 + (lane&31)][ci = cc*16 + (lane>>5)*8 + j][kk]
// (A-fragment for mfma_f32_32x32x16_bf16; verified correct in R2/R3.)
__global__ __launch_bounds__(256) void prep_weights(
        const float* __restrict__ w0, const float* __restrict__ w1,
        const float* __restrict__ w2, const float* __restrict__ w3,
        unsigned short* __restrict__ wf)
{
    const int idx = blockIdx.x * 256 + threadIdx.x;   // 73728 total
    const int lane = idx & 63;
    const int cc   = (idx >> 6) & 7;
    const int kq   = idx >> 9;        // 0..143
    const int kk   = kq % 9;
    const int ctp  = kq / 9;          // pass*4 + ct
    const int ct   = ctp & 3, p = ctp >> 2;
    const float* w = (p == 0) ? w0 : (p == 1) ? w1 : (p == 2) ? w2 : w3;
    const int co  = ct * 32 + (lane & 31);
    const int ci0 = cc * 16 + (lane >> 5) * 8;
    unsigned short tmp[8];
    #pragma unroll
    for (int j = 0; j < 8; ++j)
        tmp[j] = f2bf(w[(size_t)(co * C_ + ci0 + j) * 9 + kk]);
    *(int4*)(wf + (size_t)idx * 8) = *(const int4*)tmp;
}

// Tiled transpose of each [R][Cc] image -> [Cc][R]. Grid (Cc/32, R/32, N*C_).
template<int R, int Cc>
__global__ __launch_bounds__(256) void transpose_rc(const float* __restrict__ src,
                                                    float* __restrict__ dst)
{
    __shared__ float tile[32][33];
    const int tx = threadIdx.x, ty = threadIdx.y;          // 32 x 8
    const int c0 = blockIdx.x * 32, r0 = blockIdx.y * 32;
    const size_t img = (size_t)blockIdx.z * (R * Cc);
    const float* s = src + img;
    float* d = dst + img;
    #pragma unroll
    for (int i = 0; i < 4; ++i)
        tile[ty + i * 8][tx] = s[(size_t)(r0 + ty + i * 8) * Cc + c0 + tx];
    __syncthreads();
    #pragma unroll
    for (int i = 0; i < 4; ++i)
        d[(size_t)(c0 + ty + i * 8) * R + r0 + tx] = tile[tx][ty + i * 8];
}

// L: conv-line length; NT = L/32 tiles; RS: element stride between scan rows;
// TS: stride along the line. Ls: scan length (runtime).
template<int L, int NT, int RS, int TS>
__global__ __launch_bounds__(512, 2) void scnn_pair(
        float* __restrict__ buf,
        const unsigned short* __restrict__ wfa,
        const unsigned short* __restrict__ wfb,
        int Ls, int* __restrict__ flg_base)
{
    constexpr int TPG   = NT / 2;             // tiles per group
    constexpr int PROWS = L + 8;
    constexpr int PLSZ  = PROWS * 136;        // one row buffer, ushort units
    extern __shared__ char smem[];
    unsigned short* P = (unsigned short*)smem;                  // [2][PROWS][136]
    float* EX = (float*)(smem + (size_t)2 * PLSZ * 2);          // [4][TPG][32][32]

    const int n = blockIdx.x, role = blockIdx.y;
    int* flg = flg_base + n;
    const unsigned short* wf = role ? wfb : wfa;
    float* outn = buf + (size_t)n * CHW_;

    const int tid  = threadIdx.x;
    const int wv   = tid >> 6, lane = tid & 63;
    const int ct   = wv >> 1;         // co-tile (32 co)
    const int ch   = wv & 1;          // ci half: chunks ch*4 .. ch*4+3
    const int l31  = lane & 31, lhi = lane >> 5;

    // Hold this wave's 36 weight fragments in VGPRs for the whole pass.
    short8 A[9][4];
    #pragma unroll
    for (int kk = 0; kk < 9; ++kk)
        #pragma unroll
        for (int cc = 0; cc < 4; ++cc)
            A[kk][cc] = *(const short8*)(wf +
                ((size_t)((ct * 9 + kk) * 8 + ch * 4 + cc) * 64 + lane) * 8);

    // Zero BOTH P buffers (incl. halo rows), then fill buffer 0 interior with
    // bf16 of scan row Ls-1 (passthrough row — unmodified by either role).
    for (int i = tid; i < 2 * PROWS * 68; i += 512) ((unsigned int*)P)[i] = 0u;
    __syncthreads();
    {
        const size_t rb0 = (size_t)(Ls - 1) * RS;
        for (int i = tid; i < C_ * L; i += 512) {
            int ci = i / L, t = i - ci * L;
            P[(t + 4) * 136 + ci] = f2bf(outn[(size_t)ci * HW_ + rb0 + (size_t)t * TS]);
        }
    }
    __syncthreads();

    const int pbase = l31 * 136 + ch * 64 + lhi * 8;   // ushort units
    const int rfin  = ch * 8;          // this wave finalizes acc regs [rfin, rfin+8)
    const int rpart = 8 - rfin;        // and hands off regs [rpart, rpart+8)

    for (int s = 0; s < Ls - 1; ++s) {
        const size_t rbase = (size_t)(Ls - 2 - s) * RS;
        const unsigned short* plc = P + (s & 1) * PLSZ;         // prev row (read)
        unsigned short* pld       = P + ((s & 1) ^ 1) * PLSZ;   // this row (write)

        if (role == 1) {
            if (tid == 0) {
                int guard = 0;
                while (atomicAdd(flg, 0) < s + 1 && ++guard < (1 << 22))
                    __builtin_amdgcn_s_sleep(2);
                __threadfence();   // acquire: invalidate caches before reading x
            }
            __syncthreads();
        }

        #pragma unroll
        for (int g = 0; g < 2; ++g) {
            // x prefetch (only the rows this wave finalizes)
            float xr[TPG * 8];
            #pragma unroll
            for (int tt2 = 0; tt2 < TPG; ++tt2) {
                const int tt = g * TPG + tt2;
                #pragma unroll
                for (int q = 0; q < 8; ++q) {
                    const int r  = rfin + q;
                    const int co = ct * 32 + (r & 3) + 8 * (r >> 2) + 4 * lhi;
                    xr[tt2 * 8 + q] =
                        outn[(size_t)co * HW_ + rbase + (size_t)(tt * 32 + l31) * TS];
                }
            }

            f32x16 acc[TPG];
            #pragma unroll
            for (int tt2 = 0; tt2 < TPG; ++tt2)
                #pragma unroll
                for (int r = 0; r < 16; ++r) acc[tt2][r] = 0.f;

            #pragma unroll
            for (int kk = 0; kk < 9; ++kk)
                #pragma unroll
                for (int cc = 0; cc < 4; ++cc)
                    #pragma unroll
                    for (int tt2 = 0; tt2 < TPG; ++tt2) {
                        const unsigned short* bp = plc + pbase
                            + ((g * TPG + tt2) * 32 + kk) * 136 + cc * 16;
                        acc[tt2] = __builtin_amdgcn_mfma_f32_32x32x16_bf16(
                                       A[kk][cc], *(const short8*)bp, acc[tt2], 0, 0, 0);
                    }

            // hand off the row-half the partner finalizes
            #pragma unroll
            for (int tt2 = 0; tt2 < TPG; ++tt2)
                #pragma unroll
                for (int q = 0; q < 8; ++q) {
                    const int r  = rpart + q;
                    const int rw = (r & 3) + 8 * (r >> 2) + 4 * lhi;
                    EX[((ct * TPG + tt2) * 32 + rw) * 32 + l31] = acc[tt2][r];
                }
            __syncthreads();

            // finalize own row-half: v = x + relu(acc + partner partial)
            #pragma unroll
            for (int tt2 = 0; tt2 < TPG; ++tt2) {
                const int tpos = (g * TPG + tt2) * 32 + l31;
                #pragma unroll
                for (int q = 0; q < 8; q += 2) {
                    const int r  = rfin + q;
                    const int rw = (r & 3) + 8 * (r >> 2) + 4 * lhi;
                    const int co = ct * 32 + rw;
                    float p0 = acc[tt2][r]     + EX[((ct * TPG + tt2) * 32 + rw    ) * 32 + l31];
                    float p1 = acc[tt2][r + 1] + EX[((ct * TPG + tt2) * 32 + rw + 1) * 32 + l31];
                    float v0 = xr[tt2 * 8 + q]     + fmaxf(p0, 0.f);
                    float v1 = xr[tt2 * 8 + q + 1] + fmaxf(p1, 0.f);
                    outn[(size_t)co * HW_ + rbase + (size_t)tpos * TS]       = v0;
                    outn[(size_t)(co + 1) * HW_ + rbase + (size_t)tpos * TS] = v1;
                    *(unsigned int*)(pld + (tpos + 4) * 136 + co) =
                        (unsigned int)f2bf(v0) | ((unsigned int)f2bf(v1) << 16);
                }
            }
            __syncthreads();
        }

        if (role == 0 && tid == 0) {
            __threadfence();          // release: stores drained by the barrier above
            atomicExch(flg, s + 1);
        }
    }
}

extern "C" void kernel_launch(void* const* d_in, const int* in_sizes, int n_in,
                              void* d_out, int out_size, void* d_ws, size_t ws_size,
                              hipStream_t stream)
{
    const float* x    = (const float*)d_in[0];
    const float* w_ud = (const float*)d_in[1];
    const float* w_du = (const float*)d_in[2];
    const float* w_lr = (const float*)d_in[3];
    const float* w_rl = (const float*)d_in[4];
    float* out = (float*)d_out;

    unsigned short* wf = (unsigned short*)d_ws;              // 1,179,648 B
    int* flags = (int*)((char*)d_ws + (1536u * 1024u));      // 8 ints
    const size_t WS2_OFF = 2u * 1024u * 1024u;
    float* ws2 = (float*)((char*)d_ws + WS2_OFF);            // 48 MiB
    const bool use_tr = ws_size >= WS2_OFF + sizeof(float) * (size_t)N_ * CHW_;

    constexpr int SH_V = 2 * (192 + 8) * 136 * 2 + 4 * 3 * 4096; // 157,952 B
    constexpr int SH_H = 2 * (128 + 8) * 136 * 2 + 4 * 2 * 4096; // 106,752 B
    hipFuncSetAttribute(reinterpret_cast<const void*>(&scnn_pair<192,6,192,1>),
                        hipFuncAttributeMaxDynamicSharedMemorySize, SH_V);
    hipFuncSetAttribute(reinterpret_cast<const void*>(&scnn_pair<128,4,128,1>),
                        hipFuncAttributeMaxDynamicSharedMemorySize, SH_H);
    hipFuncSetAttribute(reinterpret_cast<const void*>(&scnn_pair<128,4,1,192>),
                        hipFuncAttributeMaxDynamicSharedMemorySize, SH_H);

    hipMemsetAsync(flags, 0, 8 * sizeof(int), stream);
    hipMemcpyAsync(out, x, sizeof(float) * (size_t)N_ * CHW_,
                   hipMemcpyDeviceToDevice, stream);
    prep_weights<<<288, 256, 0, stream>>>(w_ud, w_du, w_lr, w_rl, wf);

    constexpr size_t WFP = 4 * (9 * 8 * 64 * 8);   // frag ushorts per pass
    dim3 pg(N_, 2);

    // Passes 1+2 (vertical), pipelined one row apart.
    scnn_pair<192,6,192,1><<<pg, 512, SH_V, stream>>>(out, wf, wf + WFP, H_, flags);

    if (use_tr) {
        transpose_rc<H_, W_><<<dim3(W_/32, H_/32, N_*C_), dim3(32,8), 0, stream>>>(out, ws2);
        // Passes 3+4 (horizontal on transposed copy), pipelined.
        scnn_pair<128,4,128,1><<<pg, 512, SH_H, stream>>>(ws2, wf + 2*WFP, wf + 3*WFP, W_, flags + 4);
        transpose_rc<W_, H_><<<dim3(H_/32, W_/32, N_*C_), dim3(32,8), 0, stream>>>(ws2, out);
    } else {
        scnn_pair<128,4,1,192><<<pg, 512, SH_H, stream>>>(out, wf + 2*WFP, wf + 3*WFP, W_, flags + 4);
    }
}